// Round 1
// baseline (123.026 us; speedup 1.0000x reference)
//
#include <hip/hip_runtime.h>

// DCN CrossLayer: B=16384, F=1024, L=3, fp32.
// xl_{i+1} = x0 * (xl . w_i) + b_i + xl
//
// Strategy: one 64-lane wave per row. Each lane holds 16 elements of x0 and
// xl in registers (4x float4, coalesced 16B/lane loads). Per layer: lane-local
// partial dot (16 FMAs) -> 6-step wave butterfly reduction (__shfl_xor over
// width 64) -> register-resident elementwise update. No LDS, no barriers.
// w/b (12 KB total) are re-read per block but fully L1/L2 cached.
// Memory-bound: 128 MiB mandatory HBM traffic -> ~21 us floor at 6.3 TB/s.

constexpr int B = 16384;
constexpr int F = 1024;
constexpr int L = 3;
constexpr int ROWS_PER_BLOCK = 4;   // 4 waves/block, 1 row/wave
constexpr int BLOCK = 64 * ROWS_PER_BLOCK;

__global__ __launch_bounds__(BLOCK) void cross_layer_kernel(
    const float* __restrict__ x,        // [B, F]
    const float* __restrict__ kernels,  // [L, F] (trailing 1-dim dropped)
    const float* __restrict__ bias,     // [L, F]
    float* __restrict__ out)            // [B, F]
{
    const int lane = threadIdx.x & 63;
    const int wave = threadIdx.x >> 6;
    const int row  = blockIdx.x * ROWS_PER_BLOCK + wave;
    if (row >= B) return;

    // float4 view of this row: F/4 = 256 vec4 elements; lane handles
    // vec4 indices {c*64 + lane : c in 0..3} -> fully coalesced.
    const float4* xrow = (const float4*)(x + (size_t)row * F);

    float4 x0[4], xl[4];
#pragma unroll
    for (int c = 0; c < 4; ++c) {
        x0[c] = xrow[c * 64 + lane];
        xl[c] = x0[c];
    }

#pragma unroll
    for (int l = 0; l < L; ++l) {
        const float4* wv = (const float4*)(kernels + (size_t)l * F);
        const float4* bv = (const float4*)(bias    + (size_t)l * F);
        float4 w[4], b[4];
#pragma unroll
        for (int c = 0; c < 4; ++c) {
            w[c] = wv[c * 64 + lane];
            b[c] = bv[c * 64 + lane];
        }

        // lane-local partial dot product
        float s = 0.0f;
#pragma unroll
        for (int c = 0; c < 4; ++c) {
            s = fmaf(xl[c].x, w[c].x, s);
            s = fmaf(xl[c].y, w[c].y, s);
            s = fmaf(xl[c].z, w[c].z, s);
            s = fmaf(xl[c].w, w[c].w, s);
        }

        // 64-lane butterfly reduction (wave = 64 on CDNA)
#pragma unroll
        for (int off = 32; off >= 1; off >>= 1)
            s += __shfl_xor(s, off, 64);

        // xl = x0 * s + (b + xl)
#pragma unroll
        for (int c = 0; c < 4; ++c) {
            xl[c].x = fmaf(x0[c].x, s, b[c].x + xl[c].x);
            xl[c].y = fmaf(x0[c].y, s, b[c].y + xl[c].y);
            xl[c].z = fmaf(x0[c].z, s, b[c].z + xl[c].z);
            xl[c].w = fmaf(x0[c].w, s, b[c].w + xl[c].w);
        }
    }

    float4* orow = (float4*)(out + (size_t)row * F);
#pragma unroll
    for (int c = 0; c < 4; ++c)
        orow[c * 64 + lane] = xl[c];
}

extern "C" void kernel_launch(void* const* d_in, const int* in_sizes, int n_in,
                              void* d_out, int out_size, void* d_ws, size_t ws_size,
                              hipStream_t stream) {
    const float* x       = (const float*)d_in[0];
    const float* kernels = (const float*)d_in[1];
    const float* bias    = (const float*)d_in[2];
    float* out           = (float*)d_out;

    dim3 grid(B / ROWS_PER_BLOCK);  // 4096 blocks
    dim3 block(BLOCK);              // 256 threads = 4 waves
    cross_layer_kernel<<<grid, block, 0, stream>>>(x, kernels, bias, out);
}

// Round 2
// 119.884 us; speedup vs baseline: 1.0262x; 1.0262x over previous
//
#include <hip/hip_runtime.h>

// DCN CrossLayer: B=16384, F=1024, L=3, fp32.
// Algebraic expansion of the 3-layer recurrence:
//   xl_{k+1} = x0*s_k + b_k + xl_k,  s_k = xl_k . w_k
// =>
//   d_j  = x0 . w_j               (3 independent dots on x0)
//   t01  = b0 . w1,  t02 = b0 . w2,  t12 = b1 . w2
//   s0 = d0
//   s1 = (1+s0)*d1 + t01
//   s2 = (1+s0+s1)*d2 + t02 + t12
//   out = x0*(1+s0+s1+s2) + (b0+b1+b2)
//
// One wave per row; all 6 reduction values share a single interleaved
// 6-step butterfly (1/3 the serial DS latency of the naive 3-layer chain).
// All global loads are independent and front-loaded; b is re-read from L1
// for the epilogue to keep VGPR pressure low. Memory-bound: 128 MiB
// mandatory HBM traffic -> ~21 us floor at 6.3 TB/s.

constexpr int B = 16384;
constexpr int F = 1024;
constexpr int ROWS_PER_BLOCK = 4;   // 4 waves/block, 1 row/wave
constexpr int BLOCK = 64 * ROWS_PER_BLOCK;

__global__ __launch_bounds__(BLOCK) void cross_layer_kernel(
    const float* __restrict__ x,        // [B, F]
    const float* __restrict__ kernels,  // [3, F]
    const float* __restrict__ bias,     // [3, F]
    float* __restrict__ out)            // [B, F]
{
    const int lane = threadIdx.x & 63;
    const int wave = threadIdx.x >> 6;
    const int row  = blockIdx.x * ROWS_PER_BLOCK + wave;  // grid == B/4 exactly

    const float4* xrow = (const float4*)(x + (size_t)row * F);
    const float4* w0v  = (const float4*)(kernels);
    const float4* w1v  = (const float4*)(kernels + F);
    const float4* w2v  = (const float4*)(kernels + 2 * F);
    const float4* b0v  = (const float4*)(bias);
    const float4* b1v  = (const float4*)(bias + F);
    const float4* b2v  = (const float4*)(bias + 2 * F);

    // Front-load the x row (coalesced 16B/lane).
    float4 x0[4];
#pragma unroll
    for (int c = 0; c < 4; ++c) x0[c] = xrow[c * 64 + lane];

    // 6 independent partial sums: d0,d1,d2, t01,t02,t12
    float p0 = 0.f, p1 = 0.f, p2 = 0.f, p3 = 0.f, p4 = 0.f, p5 = 0.f;
#pragma unroll
    for (int c = 0; c < 4; ++c) {
        const int i = c * 64 + lane;
        const float4 w0 = w0v[i];
        const float4 w1 = w1v[i];
        const float4 w2 = w2v[i];
        const float4 b0 = b0v[i];
        const float4 b1 = b1v[i];

        p0 = fmaf(x0[c].x, w0.x, p0); p0 = fmaf(x0[c].y, w0.y, p0);
        p0 = fmaf(x0[c].z, w0.z, p0); p0 = fmaf(x0[c].w, w0.w, p0);

        p1 = fmaf(x0[c].x, w1.x, p1); p1 = fmaf(x0[c].y, w1.y, p1);
        p1 = fmaf(x0[c].z, w1.z, p1); p1 = fmaf(x0[c].w, w1.w, p1);

        p2 = fmaf(x0[c].x, w2.x, p2); p2 = fmaf(x0[c].y, w2.y, p2);
        p2 = fmaf(x0[c].z, w2.z, p2); p2 = fmaf(x0[c].w, w2.w, p2);

        p3 = fmaf(b0.x, w1.x, p3); p3 = fmaf(b0.y, w1.y, p3);
        p3 = fmaf(b0.z, w1.z, p3); p3 = fmaf(b0.w, w1.w, p3);

        p4 = fmaf(b0.x, w2.x, p4); p4 = fmaf(b0.y, w2.y, p4);
        p4 = fmaf(b0.z, w2.z, p4); p4 = fmaf(b0.w, w2.w, p4);

        p5 = fmaf(b1.x, w2.x, p5); p5 = fmaf(b1.y, w2.y, p5);
        p5 = fmaf(b1.z, w2.z, p5); p5 = fmaf(b1.w, w2.w, p5);
    }

    // Single interleaved 6-value butterfly over 64 lanes: the 6 shuffles at
    // each step are independent, so DS latency is paid ~once per step.
#pragma unroll
    for (int off = 32; off >= 1; off >>= 1) {
        p0 += __shfl_xor(p0, off, 64);
        p1 += __shfl_xor(p1, off, 64);
        p2 += __shfl_xor(p2, off, 64);
        p3 += __shfl_xor(p3, off, 64);
        p4 += __shfl_xor(p4, off, 64);
        p5 += __shfl_xor(p5, off, 64);
    }

    // Scalar recurrence (all lanes hold the full sums).
    const float a1 = 1.f + p0;                 // 1 + s0
    const float s1 = fmaf(a1, p1, p3);         // (1+s0)*d1 + b0.w1
    const float a2 = a1 + s1;                  // 1 + s0 + s1
    const float s2 = fmaf(a2, p2, p4 + p5);    // (1+s0+s1)*d2 + (b0+b1).w2
    const float S  = a2 + s2;                  // 1 + s0 + s1 + s2

    // Epilogue: out = x0*S + (b0+b1+b2). b re-read (L1-resident, 12 KB).
    float4* orow = (float4*)(out + (size_t)row * F);
#pragma unroll
    for (int c = 0; c < 4; ++c) {
        const int i = c * 64 + lane;
        const float4 b0 = b0v[i];
        const float4 b1 = b1v[i];
        const float4 b2 = b2v[i];
        float4 o;
        o.x = fmaf(x0[c].x, S, b0.x + b1.x + b2.x);
        o.y = fmaf(x0[c].y, S, b0.y + b1.y + b2.y);
        o.z = fmaf(x0[c].z, S, b0.z + b1.z + b2.z);
        o.w = fmaf(x0[c].w, S, b0.w + b1.w + b2.w);
        orow[i] = o;
    }
}

extern "C" void kernel_launch(void* const* d_in, const int* in_sizes, int n_in,
                              void* d_out, int out_size, void* d_ws, size_t ws_size,
                              hipStream_t stream) {
    const float* x       = (const float*)d_in[0];
    const float* kernels = (const float*)d_in[1];
    const float* bias    = (const float*)d_in[2];
    float* out           = (float*)d_out;

    dim3 grid(B / ROWS_PER_BLOCK);  // 4096 blocks
    dim3 block(BLOCK);              // 256 threads = 4 waves
    cross_layer_kernel<<<grid, block, 0, stream>>>(x, kernels, bias, out);
}